// Round 3
// baseline (32424.677 us; speedup 1.0000x reference)
//
// Round 7: bisected hybrid.
// L0 = round-4 VERBATIM (shared 3x32KB windows, barriered, proven 28.0ms).
// L1 = per-wave barrier-free K-pipeline, de-risked:
//   - per-wave ring depth 3 (4 waves x 3 x 8KB = 96KB), slots wi%3
//   - counted s_waitcnt vmcnt(8) steady / (0) tail; prefetch distance 2
//   - round-4 register budget: bw1[20] in regs + 4 windows parked (48KB LDS),
//     single-a reads (no a[8] batch)
//   - sched_barrier(0) after every inline-asm wait (rule-18 insurance)
//   - lgkmcnt(0) before each DMA issue (read-before-overwrite airtight)
#include <hip/hip_runtime.h>

#define TSTEPS 1024
#define BATCH  128
#define HDIM   1536
#define NB_L0  96
#define NB_L1  128
#define NBLK   (NB_L0 + NB_L1)
#define K0P    1600    // L0 packed K: [0,64)=x+pad, [64,1600)=W_hh0
#define K1P    3072    // L1 packed K: [0,1536)=W_ih1, [1536,3072)=W_hh1

typedef _Float16 f16x8 __attribute__((ext_vector_type(8)));
typedef float    f32x4 __attribute__((ext_vector_type(4)));

// ---- workspace layout (bytes) ----
#define OFF_C0   0ul                                    // 8 lines x 128B
#define OFF_C1   1024ul                                 // 8 lines x 128B
#define OFF_H0   4096ul                                 // ring of 4 slots
#define OFF_H1   (OFF_H0 + 4ul*BATCH*HDIM*2)            // 2 slots
#define OFF_WP0  (OFF_H1 + 2ul*BATCH*HDIM*2)
#define OFF_WP1  (OFF_WP0 + 96ul*64*K0P*2)
#define OFF_WLP  (OFF_WP1 + 128ul*48*K1P*2)
#define WS_NEED  (OFF_WLP + 16ul*HDIM*2)                // ~59.8 MB

// ---- dynamic LDS layout (bytes) — round-4 map ----
// L0: staging 3 x 32KB at [0,98304).  L1: per-wave rings 4 x 3 x 8KB = [0,98304).
#define SM_PARK  98304     // L1 park: 16 chunks x 3KB = 48KB
#define SM_CST   147456    // L0: 8KB cell state; L1: 3KB
#define SM_BG    155648
#define SM_BYTES 155904

#define MFMA(a,b,c) __builtin_amdgcn_mfma_f32_16x16x32_f16(a,b,c,0,0,0)
#define LDSBAR()  asm volatile("s_waitcnt lgkmcnt(0)\n\ts_barrier" ::: "memory")
#define WAITVM(n) asm volatile("s_waitcnt vmcnt(" #n ")" ::: "memory")
#define WAITLGKM() asm volatile("s_waitcnt lgkmcnt(0)" ::: "memory")
#define SCHB()    __builtin_amdgcn_sched_barrier(0)

__device__ __forceinline__ float sgf(float x) { return 1.f/(1.f + __expf(-x)); }
__device__ __forceinline__ float thf(float x) { float e = __expf(2.f*x); return 1.f - 2.f/(e+1.f); }

__device__ __forceinline__ void gld16(const _Float16* g, char* lds) {
  __builtin_amdgcn_global_load_lds(
      (const __attribute__((address_space(1))) unsigned int*)g,
      (__attribute__((address_space(3))) unsigned int*)lds, 16, 0, 0);
}

// Group barrier: add 1 to my line (release), spin until all 8 lines hit
// per-line target, acquire, resync.
__device__ __forceinline__ void group_bar(unsigned* lines, unsigned target, int tid) {
  __syncthreads();   // all stores (incl. h) issued; drains vmcnt/lgkm
  if (tid == 0)
    __hip_atomic_fetch_add(lines + (blockIdx.x & 7)*32, 1u,
                           __ATOMIC_RELEASE, __HIP_MEMORY_SCOPE_AGENT);
  if (tid < 8) {
    while (__hip_atomic_load(lines + tid*32, __ATOMIC_RELAXED,
                             __HIP_MEMORY_SCOPE_AGENT) < target)
      __builtin_amdgcn_s_sleep(1);
    __builtin_amdgcn_fence(__ATOMIC_ACQUIRE, "agent");
  }
  __syncthreads();
}

// Cross-group wait (no add): poll other group's 8 lines to target, acquire.
__device__ __forceinline__ void wait_group(unsigned* lines, unsigned target, int tid) {
  if (tid < 8) {
    while (__hip_atomic_load(lines + tid*32, __ATOMIC_RELAXED,
                             __HIP_MEMORY_SCOPE_AGENT) < target)
      __builtin_amdgcn_s_sleep(1);
    __builtin_amdgcn_fence(__ATOMIC_ACQUIRE, "agent");
  }
  __syncthreads();
}

// ---- weight repack fp32 -> fp16 into per-block packed rows ----
__global__ void convert_weights(const float* __restrict__ Wih0, const float* __restrict__ Whh0,
                                const float* __restrict__ Wih1, const float* __restrict__ Whh1,
                                const float* __restrict__ Wlin,
                                _Float16* __restrict__ Wp0, _Float16* __restrict__ Wp1,
                                _Float16* __restrict__ Wlp) {
  const unsigned N0 = 96u*64u*K0P, N1 = 128u*48u*K1P, N2 = 16u*HDIM;
  const unsigned NT = N0 + N1 + N2;
  for (unsigned i = blockIdx.x*blockDim.x + threadIdx.x; i < NT; i += gridDim.x*blockDim.x) {
    if (i < N0) {           // L0: [blk 96][p 64][k 1600], p = gate*16 + j
      unsigned blk = i / (64u*K0P), r = i - blk*64u*K0P;
      unsigned p = r / K0P, kk = r - p*K0P;
      unsigned srow = (p>>4)*HDIM + blk*16 + (p&15);
      float v;
      if (kk < 64u) v = (kk < 6u) ? Wih0[srow*6 + kk] : 0.f;
      else          v = Whh0[(size_t)srow*HDIM + (kk-64u)];
      Wp0[i] = (_Float16)v;
    } else if (i < N0 + N1) { // L1: [blk 128][p 48][k 3072], p = gate*12 + j
      unsigned ii = i - N0;
      unsigned blk = ii / (48u*K1P), r = ii - blk*48u*K1P;
      unsigned p = r / K1P, kk = r - p*K1P;
      unsigned srow = (p/12u)*HDIM + blk*12 + (p%12u);
      float v = (kk < (unsigned)HDIM) ? Wih1[(size_t)srow*HDIM + kk]
                                      : Whh1[(size_t)srow*HDIM + (kk-HDIM)];
      Wp1[ii] = (_Float16)v;
    } else {                 // final linear 16 x 1536 (rows >=5 zero)
      unsigned ii = i - N0 - N1;
      unsigned rr = ii / HDIM, k = ii - rr*HDIM;
      Wlp[ii] = (_Float16)(rr < 5 ? Wlin[rr*HDIM + k] : 0.f);
    }
  }
}

__global__ __launch_bounds__(256, 1) void lstm_persistent(
    const float* __restrict__ xall,
    const float* __restrict__ bih0, const float* __restrict__ bhh0,
    const float* __restrict__ bih1, const float* __restrict__ bhh1,
    const float* __restrict__ blin,
    const _Float16* __restrict__ Wp0, const _Float16* __restrict__ Wp1,
    const _Float16* __restrict__ Wlp,
    _Float16* __restrict__ h0b, _Float16* __restrict__ h1b,
    unsigned* __restrict__ c0l, unsigned* __restrict__ c1l,
    float* __restrict__ out)
{
  extern __shared__ __align__(16) char smem[];
  float* cst  = (float*)(smem + SM_CST);
  float* bg   = (float*)(smem + SM_BG);
  float* gbuf = (float*)smem;            // epilogue overlay on staging

  const int tid = threadIdx.x, bid = blockIdx.x;
  const int wv = tid >> 6, lane = tid & 63, q = lane >> 4, l15 = lane & 15;
  const int BH = BATCH*HDIM;

  if (bid < NB_L0) {
    // ============ LAYER 0 (round-4 verbatim): shared windows, barriered =====
    // DMA lane offsets: instr i stages rows [wv*32+i*4, +4), swizzled cols.
    int dmaoff[8];
#pragma unroll
    for (int i = 0; i < 8; ++i) {
      int m = wv*32 + i*4 + (lane>>4), w16 = lane & 15;
      int u = (w16 & 8) | ((w16 ^ (m & 7)) & 7);
      dmaoff[i] = m*HDIM + u*8;
    }
    const int uA = wv*4 + q;
    int addrA[8];
#pragma unroll
    for (int mt = 0; mt < 8; ++mt) {
      int m = mt*16 + l15;
      int swz = (uA & 8) | ((uA ^ (m & 7)) & 7);
      addrA[mt] = m*256 + swz*16;
    }

    for (int p = tid; p < 64; p += 256) {
      int srow = (p>>4)*HDIM + (bid<<4) + (p&15);
      bg[p] = bih0[srow] + bhh0[srow];
    }
    for (int i = tid; i < BATCH*16; i += 256) cst[i] = 0.f;
    f16x8 bw[13][4];
#pragma unroll
    for (int wi = 0; wi < 13; ++wi)
#pragma unroll
      for (int nt = 0; nt < 4; ++nt)
        bw[wi][nt] = *(const f16x8*)(Wp0 + ((size_t)(bid*64 + nt*16 + l15))*K0P
                                         + (4*wi + wv)*32 + q*8);
    __syncthreads();

#pragma unroll 1
    for (int s = 0; s < TSTEPS; ++s) {
      // ring-overwrite guard: slot s&3 was read by L1 step s-3; wait it done.
      if (s >= 4) wait_group(c1l, 16u*(unsigned)(s-3), tid);

      const _Float16* h0r = h0b + (size_t)((s+3)&3)*BH;   // h0(s-1)
      _Float16*       h0w = h0b + (size_t)(s&3)*BH;       // h0(s)
      const float*    xs  = xall + (size_t)s*BATCH*6;

      // ---- prologue: DMA window1; plain-stage window0 (x-part + h cols 0..63)
#pragma unroll
      for (int i = 0; i < 8; ++i)
        gld16(h0r + 64 + dmaoff[i], smem + 32768 + (wv*8+i)*1024);
#pragma unroll
      for (int i = 0; i < 4; ++i) {          // x-part, slots u<8 of window0
        int sidx = i*256 + tid, m = sidx>>3, w8 = sidx&7;
        int u = w8 ^ (m & 7);
        f16x8 v = {0,0,0,0,0,0,0,0};
        if (u == 0) {
#pragma unroll
          for (int j = 0; j < 6; ++j) v[j] = (_Float16)xs[m*6 + j];
        }
        *(f16x8*)(smem + m*256 + w8*16) = v;
      }
#pragma unroll
      for (int i = 0; i < 4; ++i) {          // h cols [0,64) -> slots w in [8,16)
        int sidx = i*256 + tid, m = sidx>>3, w8 = sidx&7;
        int u8 = (w8 ^ (m & 7)) & 7;
        f16x8 hv = *(const f16x8*)(h0r + m*HDIM + u8*8);
        *(f16x8*)(smem + m*256 + (8 + w8)*16) = hv;
      }
      f32x4 acc[8][4];
#pragma unroll
      for (int mt = 0; mt < 8; ++mt)
#pragma unroll
        for (int nt = 0; nt < 4; ++nt) { f32x4 z = {0,0,0,0}; acc[mt][nt] = z; }

      // ---- K-loop: 13 windows
#pragma unroll
      for (int wi = 0; wi < 13; ++wi) {
        if (wi == 12)      WAITVM(0);
        else if (wi >= 1)  WAITVM(8);
        LDSBAR();
        if (wi + 2 < 13) {                   // DMA window wi+2 (cols 128w-64)
          const _Float16* src = h0r + (wi+2)*128 - 64;
          char* dst = smem + ((wi+2)%3)*32768;
#pragma unroll
          for (int i = 0; i < 8; ++i) gld16(src + dmaoff[i], dst + (wv*8+i)*1024);
        }
        if (4*wi + wv < 50) {                // wave's chunk exists
          const char* bs = smem + (wi%3)*32768;
#pragma unroll
          for (int mt = 0; mt < 8; ++mt) {
            f16x8 a = *(const f16x8*)(bs + addrA[mt]);
#pragma unroll
            for (int nt = 0; nt < 4; ++nt)
              acc[mt][nt] = MFMA(a, bw[wi][nt], acc[mt][nt]);
          }
        }
      }
      LDSBAR();

      // ---- staggered K-reduction into gbuf [64 cols][stride 132 f32]
#pragma unroll
      for (int r = 0; r < 4; ++r) {
        int nt = (wv + r) & 3;
#pragma unroll
        for (int mt = 0; mt < 8; ++mt) {
          f32x4 av = (nt==0)?acc[mt][0]:(nt==1)?acc[mt][1]:(nt==2)?acc[mt][2]:acc[mt][3];
          float* p = gbuf + (nt*16 + l15)*132 + (mt*16 + q*4);
          if (r == 0) *(f32x4*)p = av;
          else        { f32x4 o = *(const f32x4*)p; *(f32x4*)p = o + av; }
        }
        LDSBAR();
      }
      // ---- cell update + h0 write
#pragma unroll
      for (int e = 0; e < 8; ++e) {
        int idx = e*256 + tid, m = idx>>4, j = idx&15;
        float gi = gbuf[j*132 + m]        + bg[j];
        float gf = gbuf[(16+j)*132 + m]   + bg[16+j];
        float gg = gbuf[(32+j)*132 + m]   + bg[32+j];
        float go = gbuf[(48+j)*132 + m]   + bg[48+j];
        float co = cst[m*16 + j];
        float cn = sgf(gf)*co + sgf(gi)*thf(gg);
        cst[m*16 + j] = cn;
        h0w[(size_t)m*HDIM + (bid<<4) + j] = (_Float16)(sgf(go)*thf(cn));
      }
      group_bar(c0l, 12u*(unsigned)(s+1), tid);   // L0-only barrier
    }
  } else {
    // ============ LAYER 1: per-wave barrier-free pipeline, ring depth 3 =====
    const int bid1 = bid - NB_L0;
    char* park = smem + SM_PARK;
    char* const ring = smem + wv*24576;    // this wave's 3-slot private ring

    // DMA per-lane source offsets (f16 units) for the 8 gld16 of one 128x32
    // chunk. instr i covers rows [i*16,+16); lane -> (row = i*16 + lane>>2,
    // sub-chunk c = (lane&3) ^ ((lane>>4)&3)); LDS dest linear (base+lane*16)
    // => LDS(row,c) = row*64 + (c ^ ((row>>2)&3))*16.
    int dmaoff2[8];
#pragma unroll
    for (int i = 0; i < 8; ++i)
      dmaoff2[i] = (i*16 + (lane>>2))*HDIM + (((lane&3) ^ ((lane>>4)&3))<<3);
    // A-read: row = mt*16+l15, sub c=q at swizzled pos q ^ (l15>>2).
    const int aOff = l15*64 + ((q ^ (l15>>2))<<4);

    for (int p = tid; p < 48; p += 256) {
      int srow = (p/12)*HDIM + bid1*12 + (p%12);
      bg[p] = bih1[srow] + bhh1[srow];
    }
    for (int i = tid; i < 64*12; i += 256) cst[i] = 0.f;
    f16x8 bw1[20][3];                        // windows 0..19 in regs
#pragma unroll
    for (int wi = 0; wi < 20; ++wi)
#pragma unroll
      for (int nt = 0; nt < 3; ++nt)
        bw1[wi][nt] = *(const f16x8*)(Wp1 + ((size_t)(bid1*48 + nt*16 + l15))*K1P
                                          + (4*wi + wv)*32 + q*8);
    // windows 20..23 parked in LDS: park[cl][nt][lane], cl = (wi-20)*4 + wv
    for (int idx = tid; idx < 16*3*64; idx += 256) {
      int cl = idx/192, rem = idx - cl*192, nt = rem>>6, l = rem&63;
      f16x8 v = *(const f16x8*)(Wp1 + ((size_t)(bid1*48 + nt*16 + (l&15)))*K1P
                                    + (80 + cl)*32 + (l>>4)*8);
      *(f16x8*)(park + idx*16) = v;
    }
    __syncthreads();

#pragma unroll 1
    for (int s = 1; s <= TSTEPS; ++s) {
      // need h0(s-1): L0 finished step s-1 <=> c0 lines >= 12*s
      wait_group(c0l, 12u*(unsigned)s, tid);

      const _Float16* h0r = h0b + (size_t)((s-1)&3)*BH;   // h0(s-1)
      const _Float16* h1r = h1b + (size_t)(s&1)*BH;       // h1(s-2)
      _Float16*       h1w = h1b + (size_t)((s-1)&1)*BH;   // h1(s-1)

      // issue one window chunk for this wave (8 gld16 = 8 vmcnt ops)
      auto issue1 = [&](int wn) {
        const _Float16* src = (wn < 12) ? (h0r + wn*128 + wv*32)
                                        : (h1r + (wn-12)*128 + wv*32);
        char* dst = ring + (wn%3)*8192;
#pragma unroll
        for (int i = 0; i < 8; ++i) gld16(src + dmaoff2[i], dst + i*1024);
      };
      issue1(0); issue1(1);                  // prologue: 2 windows in flight

      f32x4 acc[8][3];
#pragma unroll
      for (int mt = 0; mt < 8; ++mt)
#pragma unroll
        for (int nt = 0; nt < 3; ++nt) { f32x4 z = {0,0,0,0}; acc[mt][nt] = z; }

      // ---- K-loop: 24 windows, per-wave pipeline, NO barriers
#pragma unroll
      for (int wi = 0; wi < 24; ++wi) {
        if (wi == 23) WAITVM(0); else WAITVM(8);
        SCHB();
        const char* bs = ring + (wi%3)*8192;
        if (wi < 20) {
#pragma unroll
          for (int mt = 0; mt < 8; ++mt) {
            f16x8 a = *(const f16x8*)(bs + mt*1024 + aOff);
            acc[mt][0] = MFMA(a, bw1[wi][0], acc[mt][0]);
            acc[mt][1] = MFMA(a, bw1[wi][1], acc[mt][1]);
            acc[mt][2] = MFMA(a, bw1[wi][2], acc[mt][2]);
          }
        } else {
          const int cl = (wi-20)*4 + wv;
          f16x8 p0 = *(const f16x8*)(park + ((cl*3+0)*64 + lane)*16);
          f16x8 p1 = *(const f16x8*)(park + ((cl*3+1)*64 + lane)*16);
          f16x8 p2 = *(const f16x8*)(park + ((cl*3+2)*64 + lane)*16);
#pragma unroll
          for (int mt = 0; mt < 8; ++mt) {
            f16x8 a = *(const f16x8*)(bs + mt*1024 + aOff);
            acc[mt][0] = MFMA(a, p0, acc[mt][0]);
            acc[mt][1] = MFMA(a, p1, acc[mt][1]);
            acc[mt][2] = MFMA(a, p2, acc[mt][2]);
          }
        }
        WAITLGKM();                          // this window's reads landed
        SCHB();
        if (wi + 2 < 24) issue1(wi + 2);     // slot (wi+2)%3 = (wi-1)%3: done
      }
      LDSBAR();

      // ---- staggered K-reduction (3 ntiles)
#pragma unroll
      for (int r = 0; r < 4; ++r) {
        int nt = (wv + r) & 3;
        if (nt < 3) {
#pragma unroll
          for (int mt = 0; mt < 8; ++mt) {
            f32x4 av = (nt==0)?acc[mt][0]:(nt==1)?acc[mt][1]:acc[mt][2];
            float* p = gbuf + (nt*16 + l15)*132 + (mt*16 + q*4);
            if (r == 0) *(f32x4*)p = av;
            else        { f32x4 o = *(const f32x4*)p; *(f32x4*)p = o + av; }
          }
        }
        LDSBAR();
      }
#pragma unroll
      for (int e = 0; e < 8; ++e) {
        int idx = e*256 + tid, m = idx>>4, j = idx&15;
        if (j < 12) {
          float gi = gbuf[j*132 + m]        + bg[j];
          float gf = gbuf[(12+j)*132 + m]   + bg[12+j];
          float gg = gbuf[(24+j)*132 + m]   + bg[24+j];
          float go = gbuf[(36+j)*132 + m]   + bg[36+j];
          float co = cst[m*12 + j];
          float cn = sgf(gf)*co + sgf(gi)*thf(gg);
          cst[m*12 + j] = cn;
          h1w[(size_t)m*HDIM + bid1*12 + j] = (_Float16)(sgf(go)*thf(cn));
        }
      }
      group_bar(c1l, 16u*(unsigned)s, tid);   // L1-only barrier
    }

    // ---- final linear: out = h1(T-1) @ Wlin^T + blin (first L1 block) ----
    if (bid == NB_L0) {
      const _Float16* h1r = h1b + (size_t)((TSTEPS-1)&1)*BH;
      f32x4 a8[8];
#pragma unroll
      for (int i = 0; i < 8; ++i) { f32x4 z = {0,0,0,0}; a8[i] = z; }
      for (int c = wv*12; c < wv*12 + 12; ++c) {
        f16x8 bf = *(const f16x8*)(Wlp + (size_t)l15*HDIM + c*32 + q*8);
#pragma unroll
        for (int mt = 0; mt < 8; ++mt) {
          f16x8 a = *(const f16x8*)(h1r + (size_t)(mt*16 + l15)*HDIM + c*32 + q*8);
          a8[mt] = MFMA(a, bf, a8[mt]);
        }
      }
      float* pl = (float*)smem;
#pragma unroll
      for (int mt = 0; mt < 8; ++mt)
#pragma unroll
        for (int rg = 0; rg < 4; ++rg)
          pl[wv*2048 + (mt*16 + q*4 + rg)*16 + l15] = a8[mt][rg];
      __syncthreads();
      for (int e = tid; e < 640; e += 256) {
        int b = e/5, o = e - 5*b;
        out[e] = blin[o] + pl[b*16+o] + pl[2048 + b*16+o] + pl[4096 + b*16+o] + pl[6144 + b*16+o];
      }
    }
  }
}

extern "C" void kernel_launch(void* const* d_in, const int* in_sizes, int n_in,
                              void* d_out, int out_size, void* d_ws, size_t ws_size,
                              hipStream_t stream) {
  (void)in_sizes; (void)n_in; (void)out_size;
  if (ws_size < WS_NEED) return;

  const float* x    = (const float*)d_in[0];
  const float* Wih0 = (const float*)d_in[1];
  const float* Whh0 = (const float*)d_in[2];
  const float* bih0 = (const float*)d_in[3];
  const float* bhh0 = (const float*)d_in[4];
  const float* Wih1 = (const float*)d_in[5];
  const float* Whh1 = (const float*)d_in[6];
  const float* bih1 = (const float*)d_in[7];
  const float* bhh1 = (const float*)d_in[8];
  const float* Wlin = (const float*)d_in[9];
  const float* blin = (const float*)d_in[10];

  char* ws = (char*)d_ws;
  unsigned*  c0l = (unsigned*)(ws + OFF_C0);
  unsigned*  c1l = (unsigned*)(ws + OFF_C1);
  _Float16*  h0b = (_Float16*)(ws + OFF_H0);
  _Float16*  h1b = (_Float16*)(ws + OFF_H1);
  _Float16*  Wp0 = (_Float16*)(ws + OFF_WP0);
  _Float16*  Wp1 = (_Float16*)(ws + OFF_WP1);
  _Float16*  Wlp = (_Float16*)(ws + OFF_WLP);
  float*     out = (float*)d_out;

  hipMemsetAsync(ws, 0, OFF_WP0, stream);   // counters + h rings
  hipLaunchKernelGGL(convert_weights, dim3(4096), dim3(256), 0, stream,
                     Wih0, Whh0, Wih1, Whh1, Wlin, Wp0, Wp1, Wlp);

  hipFuncSetAttribute((const void*)lstm_persistent,
                      hipFuncAttributeMaxDynamicSharedMemorySize, 160*1024);

  void* args[14];
  args[0]  = (void*)&x;    args[1]  = (void*)&bih0; args[2]  = (void*)&bhh0;
  args[3]  = (void*)&bih1; args[4]  = (void*)&bhh1; args[5]  = (void*)&blin;
  args[6]  = (void*)&Wp0;  args[7]  = (void*)&Wp1;  args[8]  = (void*)&Wlp;
  args[9]  = (void*)&h0b;  args[10] = (void*)&h1b;  args[11] = (void*)&c0l;
  args[12] = (void*)&c1l;  args[13] = (void*)&out;
  hipError_t err = hipLaunchCooperativeKernel((const void*)lstm_persistent,
                                              dim3(NBLK), dim3(256),
                                              args, (unsigned)SM_BYTES, stream);
  if (err != hipSuccess) {
    hipLaunchKernelGGL(lstm_persistent, dim3(NBLK), dim3(256), SM_BYTES, stream,
                       x, bih0, bhh0, bih1, bhh1, blin, Wp0, Wp1, Wlp,
                       h0b, h1b, c0l, c1l, out);
  }
}

// Round 4
// 30106.647 us; speedup vs baseline: 1.0770x; 1.0770x over previous
//
// Round 8: round-4 base (proven 28.0ms) + low-risk deltas targeting the
// LLC-traffic-bound regime identified by round-7's falsification:
//  (1) L1 K-loop reordered h1-first: windows [12..23,0..11]; the c0 wait
//      (needs h0(s-1)) moves to k==10, so ~half the step's staging+MFMA
//      runs before L0 must be done -> absorbs L0/L1 boundary jitter.
//  (2) Vectorized cell-state + h writes: 2B scalar global stores -> f16x8
//      (L0) / 3x f16x2 (L1); cst via vector LDS ops. Fewer store ops,
//      fewer partial-sector LLC RMWs.
//  (3) L1 cst init bound fix (768 -> BATCH*12 = 1536; was relying on
//      LDS happening to be zeroed).
#include <hip/hip_runtime.h>

#define TSTEPS 1024
#define BATCH  128
#define HDIM   1536
#define NB_L0  96
#define NB_L1  128
#define NBLK   (NB_L0 + NB_L1)
#define K0P    1600    // L0 packed K: [0,64)=x+pad, [64,1600)=W_hh0
#define K1P    3072    // L1 packed K: [0,1536)=W_ih1, [1536,3072)=W_hh1

typedef _Float16 f16x8 __attribute__((ext_vector_type(8)));
typedef _Float16 f16x2 __attribute__((ext_vector_type(2)));
typedef float    f32x4 __attribute__((ext_vector_type(4)));
typedef float    f32x2 __attribute__((ext_vector_type(2)));

// ---- workspace layout (bytes) ----
#define OFF_C0   0ul                                    // 8 lines x 128B
#define OFF_C1   1024ul                                 // 8 lines x 128B
#define OFF_H0   4096ul                                 // ring of 4 slots
#define OFF_H1   (OFF_H0 + 4ul*BATCH*HDIM*2)            // 2 slots
#define OFF_WP0  (OFF_H1 + 2ul*BATCH*HDIM*2)
#define OFF_WP1  (OFF_WP0 + 96ul*64*K0P*2)
#define OFF_WLP  (OFF_WP1 + 128ul*48*K1P*2)
#define WS_NEED  (OFF_WLP + 16ul*HDIM*2)                // ~59.8 MB

// ---- dynamic LDS layout (bytes) — round-4 map ----
#define SM_PARK  98304     // park: 16 chunks x 3KB = 48KB (L1 only)
#define SM_CST   147456
#define SM_BG    155648
#define SM_BYTES 155904

#define MFMA(a,b,c) __builtin_amdgcn_mfma_f32_16x16x32_f16(a,b,c,0,0,0)
#define LDSBAR()  asm volatile("s_waitcnt lgkmcnt(0)\n\ts_barrier" ::: "memory")
#define WAITVM8() asm volatile("s_waitcnt vmcnt(8)" ::: "memory")
#define WAITVM0() asm volatile("s_waitcnt vmcnt(0)" ::: "memory")

__device__ __forceinline__ float sgf(float x) { return 1.f/(1.f + __expf(-x)); }
__device__ __forceinline__ float thf(float x) { float e = __expf(2.f*x); return 1.f - 2.f/(e+1.f); }

__device__ __forceinline__ void gld16(const _Float16* g, char* lds) {
  __builtin_amdgcn_global_load_lds(
      (const __attribute__((address_space(1))) unsigned int*)g,
      (__attribute__((address_space(3))) unsigned int*)lds, 16, 0, 0);
}

// Group barrier: add 1 to my line (release), spin until all 8 lines hit
// per-line target, acquire, resync.
__device__ __forceinline__ void group_bar(unsigned* lines, unsigned target, int tid) {
  __syncthreads();   // all stores (incl. h) issued; drains vmcnt/lgkm
  if (tid == 0)
    __hip_atomic_fetch_add(lines + (blockIdx.x & 7)*32, 1u,
                           __ATOMIC_RELEASE, __HIP_MEMORY_SCOPE_AGENT);
  if (tid < 8) {
    while (__hip_atomic_load(lines + tid*32, __ATOMIC_RELAXED,
                             __HIP_MEMORY_SCOPE_AGENT) < target)
      __builtin_amdgcn_s_sleep(1);
    __builtin_amdgcn_fence(__ATOMIC_ACQUIRE, "agent");
  }
  __syncthreads();
}

// Cross-group wait (no add): poll other group's 8 lines to target, acquire.
__device__ __forceinline__ void wait_group(unsigned* lines, unsigned target, int tid) {
  if (tid < 8) {
    while (__hip_atomic_load(lines + tid*32, __ATOMIC_RELAXED,
                             __HIP_MEMORY_SCOPE_AGENT) < target)
      __builtin_amdgcn_s_sleep(1);
    __builtin_amdgcn_fence(__ATOMIC_ACQUIRE, "agent");
  }
  __syncthreads();
}

// ---- weight repack fp32 -> fp16 into per-block packed rows ----
__global__ void convert_weights(const float* __restrict__ Wih0, const float* __restrict__ Whh0,
                                const float* __restrict__ Wih1, const float* __restrict__ Whh1,
                                const float* __restrict__ Wlin,
                                _Float16* __restrict__ Wp0, _Float16* __restrict__ Wp1,
                                _Float16* __restrict__ Wlp) {
  const unsigned N0 = 96u*64u*K0P, N1 = 128u*48u*K1P, N2 = 16u*HDIM;
  const unsigned NT = N0 + N1 + N2;
  for (unsigned i = blockIdx.x*blockDim.x + threadIdx.x; i < NT; i += gridDim.x*blockDim.x) {
    if (i < N0) {           // L0: [blk 96][p 64][k 1600], p = gate*16 + j
      unsigned blk = i / (64u*K0P), r = i - blk*64u*K0P;
      unsigned p = r / K0P, kk = r - p*K0P;
      unsigned srow = (p>>4)*HDIM + blk*16 + (p&15);
      float v;
      if (kk < 64u) v = (kk < 6u) ? Wih0[srow*6 + kk] : 0.f;
      else          v = Whh0[(size_t)srow*HDIM + (kk-64u)];
      Wp0[i] = (_Float16)v;
    } else if (i < N0 + N1) { // L1: [blk 128][p 48][k 3072], p = gate*12 + j
      unsigned ii = i - N0;
      unsigned blk = ii / (48u*K1P), r = ii - blk*48u*K1P;
      unsigned p = r / K1P, kk = r - p*K1P;
      unsigned srow = (p/12u)*HDIM + blk*12 + (p%12u);
      float v = (kk < (unsigned)HDIM) ? Wih1[(size_t)srow*HDIM + kk]
                                      : Whh1[(size_t)srow*HDIM + (kk-HDIM)];
      Wp1[ii] = (_Float16)v;
    } else {                 // final linear 16 x 1536 (rows >=5 zero)
      unsigned ii = i - N0 - N1;
      unsigned rr = ii / HDIM, k = ii - rr*HDIM;
      Wlp[ii] = (_Float16)(rr < 5 ? Wlin[rr*HDIM + k] : 0.f);
    }
  }
}

__global__ __launch_bounds__(256, 1) void lstm_persistent(
    const float* __restrict__ xall,
    const float* __restrict__ bih0, const float* __restrict__ bhh0,
    const float* __restrict__ bih1, const float* __restrict__ bhh1,
    const float* __restrict__ blin,
    const _Float16* __restrict__ Wp0, const _Float16* __restrict__ Wp1,
    const _Float16* __restrict__ Wlp,
    _Float16* __restrict__ h0b, _Float16* __restrict__ h1b,
    unsigned* __restrict__ c0l, unsigned* __restrict__ c1l,
    float* __restrict__ out)
{
  extern __shared__ __align__(16) char smem[];
  char*  park = smem + SM_PARK;
  float* cst  = (float*)(smem + SM_CST);
  float* bg   = (float*)(smem + SM_BG);
  float* gbuf = (float*)smem;            // epilogue overlay on staging

  const int tid = threadIdx.x, bid = blockIdx.x;
  const int wv = tid >> 6, lane = tid & 63, q = lane >> 4, l15 = lane & 15;
  const int BH = BATCH*HDIM;

  // DMA lane offsets: instr i stages rows [wv*32+i*4, +4), swizzled cols.
  int dmaoff[8];
#pragma unroll
  for (int i = 0; i < 8; ++i) {
    int m = wv*32 + i*4 + (lane>>4), w16 = lane & 15;
    int u = (w16 & 8) | ((w16 ^ (m & 7)) & 7);
    dmaoff[i] = m*HDIM + u*8;
  }
  // A-frag LDS byte addrs within a window buffer (this wave reads chunk #wv).
  const int uA = wv*4 + q;
  int addrA[8];
#pragma unroll
  for (int mt = 0; mt < 8; ++mt) {
    int m = mt*16 + l15;
    int swz = (uA & 8) | ((uA ^ (m & 7)) & 7);
    addrA[mt] = m*256 + swz*16;
  }

  if (bid < NB_L0) {
    // ================= LAYER 0 (round-4 structure): 13 windows ==============
    for (int p = tid; p < 64; p += 256) {
      int srow = (p>>4)*HDIM + (bid<<4) + (p&15);
      bg[p] = bih0[srow] + bhh0[srow];
    }
    for (int i = tid; i < BATCH*16; i += 256) cst[i] = 0.f;
    f16x8 bw[13][4];
#pragma unroll
    for (int wi = 0; wi < 13; ++wi)
#pragma unroll
      for (int nt = 0; nt < 4; ++nt)
        bw[wi][nt] = *(const f16x8*)(Wp0 + ((size_t)(bid*64 + nt*16 + l15))*K0P
                                         + (4*wi + wv)*32 + q*8);
    __syncthreads();

#pragma unroll 1
    for (int s = 0; s < TSTEPS; ++s) {
      // ring-overwrite guard: slot s&3 was read by L1 step s-3; wait it done.
      if (s >= 4) wait_group(c1l, 16u*(unsigned)(s-3), tid);

      const _Float16* h0r = h0b + (size_t)((s+3)&3)*BH;   // h0(s-1)
      _Float16*       h0w = h0b + (size_t)(s&3)*BH;       // h0(s)
      const float*    xs  = xall + (size_t)s*BATCH*6;

      // ---- prologue: DMA window1; plain-stage window0 (x-part + h cols 0..63)
#pragma unroll
      for (int i = 0; i < 8; ++i)
        gld16(h0r + 64 + dmaoff[i], smem + 32768 + (wv*8+i)*1024);
#pragma unroll
      for (int i = 0; i < 4; ++i) {          // x-part, slots u<8 of window0
        int sidx = i*256 + tid, m = sidx>>3, w8 = sidx&7;
        int u = w8 ^ (m & 7);
        f16x8 v = {0,0,0,0,0,0,0,0};
        if (u == 0) {
#pragma unroll
          for (int j = 0; j < 6; ++j) v[j] = (_Float16)xs[m*6 + j];
        }
        *(f16x8*)(smem + m*256 + w8*16) = v;
      }
#pragma unroll
      for (int i = 0; i < 4; ++i) {          // h cols [0,64) -> slots w in [8,16)
        int sidx = i*256 + tid, m = sidx>>3, w8 = sidx&7;
        int u8 = (w8 ^ (m & 7)) & 7;
        f16x8 hv = *(const f16x8*)(h0r + m*HDIM + u8*8);
        *(f16x8*)(smem + m*256 + (8 + w8)*16) = hv;
      }
      f32x4 acc[8][4];
#pragma unroll
      for (int mt = 0; mt < 8; ++mt)
#pragma unroll
        for (int nt = 0; nt < 4; ++nt) { f32x4 z = {0,0,0,0}; acc[mt][nt] = z; }

      // ---- K-loop: 13 windows
#pragma unroll
      for (int wi = 0; wi < 13; ++wi) {
        if (wi == 12)      WAITVM0();
        else if (wi >= 1)  WAITVM8();
        LDSBAR();
        if (wi + 2 < 13) {                   // DMA window wi+2 (cols 128w-64)
          const _Float16* src = h0r + (wi+2)*128 - 64;
          char* dst = smem + ((wi+2)%3)*32768;
#pragma unroll
          for (int i = 0; i < 8; ++i) gld16(src + dmaoff[i], dst + (wv*8+i)*1024);
        }
        if (4*wi + wv < 50) {                // wave's chunk exists
          const char* bs = smem + (wi%3)*32768;
#pragma unroll
          for (int mt = 0; mt < 8; ++mt) {
            f16x8 a = *(const f16x8*)(bs + addrA[mt]);
#pragma unroll
            for (int nt = 0; nt < 4; ++nt)
              acc[mt][nt] = MFMA(a, bw[wi][nt], acc[mt][nt]);
          }
        }
      }
      LDSBAR();

      // ---- staggered K-reduction into gbuf [64 cols][stride 132 f32]
#pragma unroll
      for (int r = 0; r < 4; ++r) {
        int nt = (wv + r) & 3;
#pragma unroll
        for (int mt = 0; mt < 8; ++mt) {
          f32x4 av = (nt==0)?acc[mt][0]:(nt==1)?acc[mt][1]:(nt==2)?acc[mt][2]:acc[mt][3];
          float* p = gbuf + (nt*16 + l15)*132 + (mt*16 + q*4);
          if (r == 0) *(f32x4*)p = av;
          else        { f32x4 o = *(const f32x4*)p; *(f32x4*)p = o + av; }
        }
        LDSBAR();
      }
      // ---- cell update + h0 write (vectorized: 8 cells/thread, one f16x8 store)
      {
        const int m = tid >> 1, jb = (tid & 1) * 8;
        f32x4 cv0 = *(f32x4*)(cst + m*16 + jb);
        f32x4 cv1 = *(f32x4*)(cst + m*16 + jb + 4);
        f16x8 hv;
#pragma unroll
        for (int u = 0; u < 8; ++u) {
          int j = jb + u;
          float gi = gbuf[j*132 + m]        + bg[j];
          float gf = gbuf[(16+j)*132 + m]   + bg[16+j];
          float gg = gbuf[(32+j)*132 + m]   + bg[32+j];
          float go = gbuf[(48+j)*132 + m]   + bg[48+j];
          float co = (u < 4) ? cv0[u] : cv1[u-4];
          float cn = sgf(gf)*co + sgf(gi)*thf(gg);
          if (u < 4) cv0[u] = cn; else cv1[u-4] = cn;
          hv[u] = (_Float16)(sgf(go)*thf(cn));
        }
        *(f32x4*)(cst + m*16 + jb)     = cv0;
        *(f32x4*)(cst + m*16 + jb + 4) = cv1;
        *(f16x8*)(h0w + (size_t)m*HDIM + (bid<<4) + jb) = hv;
      }
      group_bar(c0l, 12u*(unsigned)(s+1), tid);   // L0-only barrier
    }
  } else {
    // ============ LAYER 1: h1-first window order [12..23, 0..11] ============
    const int bid1 = bid - NB_L0;
    for (int p = tid; p < 48; p += 256) {
      int srow = (p/12)*HDIM + bid1*12 + (p%12);
      bg[p] = bih1[srow] + bhh1[srow];
    }
    for (int i = tid; i < BATCH*12; i += 256) cst[i] = 0.f;   // fixed bound
    f16x8 bw1[20][3];                        // windows 0..19 in regs
#pragma unroll
    for (int wi = 0; wi < 20; ++wi)
#pragma unroll
      for (int nt = 0; nt < 3; ++nt)
        bw1[wi][nt] = *(const f16x8*)(Wp1 + ((size_t)(bid1*48 + nt*16 + l15))*K1P
                                          + (4*wi + wv)*32 + q*8);
    // windows 20..23 parked in LDS: park[cl][nt][lane], cl = (wi-20)*4 + wv
    for (int idx = tid; idx < 16*3*64; idx += 256) {
      int cl = idx/192, rem = idx - cl*192, nt = rem>>6, l = rem&63;
      f16x8 v = *(const f16x8*)(Wp1 + ((size_t)(bid1*48 + nt*16 + (l&15)))*K1P
                                    + (80 + cl)*32 + (l>>4)*8);
      *(f16x8*)(park + idx*16) = v;
    }
    __syncthreads();

#pragma unroll 1
    for (int s = 1; s <= TSTEPS; ++s) {
      const _Float16* h0r = h0b + (size_t)((s-1)&3)*BH;   // h0(s-1)
      const _Float16* h1r = h1b + (size_t)(s&1)*BH;       // h1(s-2)
      _Float16*       h1w = h1b + (size_t)((s-1)&1)*BH;   // h1(s-1)

      // prologue: DMA phys windows 12,13 (h1 cols 0..255) — no c0 wait needed
#pragma unroll
      for (int i = 0; i < 8; ++i) gld16(h1r +   0 + dmaoff[i], smem +     0 + (wv*8+i)*1024);
#pragma unroll
      for (int i = 0; i < 8; ++i) gld16(h1r + 128 + dmaoff[i], smem + 32768 + (wv*8+i)*1024);
      f32x4 acc[8][3];
#pragma unroll
      for (int mt = 0; mt < 8; ++mt)
#pragma unroll
        for (int nt = 0; nt < 3; ++nt) { f32x4 z = {0,0,0,0}; acc[mt][nt] = z; }

      // ---- K-loop: 24 windows, order p = (k+12)%24 (h1 half first).
      // c0 wait deferred to k==10: first h0-window DMA is issued there.
#pragma unroll
      for (int k = 0; k < 24; ++k) {
        if (k == 10) wait_group(c0l, 12u*(unsigned)s, tid);  // need h0(s-1) now
        if (k == 23) WAITVM0(); else WAITVM8();
        LDSBAR();
        if (k + 2 < 24) {
          int wn = (k + 14) % 24;            // phys window to fetch
          const _Float16* src = (wn < 12) ? (h0r + wn*128) : (h1r + (wn-12)*128);
          char* dst = smem + ((k+2)%3)*32768;
#pragma unroll
          for (int i = 0; i < 8; ++i) gld16(src + dmaoff[i], dst + (wv*8+i)*1024);
        }
        const char* bs = smem + (k%3)*32768;
        const int p = (k + 12) % 24;         // phys window being consumed
        if (p < 20) {
#pragma unroll
          for (int mt = 0; mt < 8; ++mt) {
            f16x8 a = *(const f16x8*)(bs + addrA[mt]);
#pragma unroll
            for (int nt = 0; nt < 3; ++nt)
              acc[mt][nt] = MFMA(a, bw1[p][nt], acc[mt][nt]);
          }
        } else {
          const int cl = (p-20)*4 + wv;
          f16x8 p0 = *(const f16x8*)(park + ((cl*3+0)*64 + lane)*16);
          f16x8 p1 = *(const f16x8*)(park + ((cl*3+1)*64 + lane)*16);
          f16x8 p2 = *(const f16x8*)(park + ((cl*3+2)*64 + lane)*16);
#pragma unroll
          for (int mt = 0; mt < 8; ++mt) {
            f16x8 a = *(const f16x8*)(bs + addrA[mt]);
            acc[mt][0] = MFMA(a, p0, acc[mt][0]);
            acc[mt][1] = MFMA(a, p1, acc[mt][1]);
            acc[mt][2] = MFMA(a, p2, acc[mt][2]);
          }
        }
      }
      LDSBAR();

      // ---- staggered K-reduction (3 ntiles)
#pragma unroll
      for (int r = 0; r < 4; ++r) {
        int nt = (wv + r) & 3;
        if (nt < 3) {
#pragma unroll
          for (int mt = 0; mt < 8; ++mt) {
            f32x4 av = (nt==0)?acc[mt][0]:(nt==1)?acc[mt][1]:acc[mt][2];
            float* p = gbuf + (nt*16 + l15)*132 + (mt*16 + q*4);
            if (r == 0) *(f32x4*)p = av;
            else        { f32x4 o = *(const f32x4*)p; *(f32x4*)p = o + av; }
          }
        }
        LDSBAR();
      }
      // ---- cell update + h1 write (vectorized: 6 cells/thread, 3x f16x2)
      {
        const int m = tid >> 1, jb = (tid & 1) * 6;
        f32x2 cv[3];
#pragma unroll
        for (int v = 0; v < 3; ++v) cv[v] = *(f32x2*)(cst + m*12 + jb + 2*v);
        f16x2 hv[3];
#pragma unroll
        for (int u = 0; u < 6; ++u) {
          int j = jb + u;
          float gi = gbuf[j*132 + m]        + bg[j];
          float gf = gbuf[(12+j)*132 + m]   + bg[12+j];
          float gg = gbuf[(24+j)*132 + m]   + bg[24+j];
          float go = gbuf[(36+j)*132 + m]   + bg[36+j];
          float co = cv[u>>1][u&1];
          float cn = sgf(gf)*co + sgf(gi)*thf(gg);
          cv[u>>1][u&1] = cn;
          hv[u>>1][u&1] = (_Float16)(sgf(go)*thf(cn));
        }
#pragma unroll
        for (int v = 0; v < 3; ++v) {
          *(f32x2*)(cst + m*12 + jb + 2*v) = cv[v];
          *(f16x2*)(h1w + (size_t)m*HDIM + bid1*12 + jb + 2*v) = hv[v];
        }
      }
      group_bar(c1l, 16u*(unsigned)s, tid);   // L1-only barrier
    }

    // ---- final linear: out = h1(T-1) @ Wlin^T + blin (first L1 block) ----
    if (bid == NB_L0) {
      const _Float16* h1r = h1b + (size_t)((TSTEPS-1)&1)*BH;
      f32x4 a8[8];
#pragma unroll
      for (int i = 0; i < 8; ++i) { f32x4 z = {0,0,0,0}; a8[i] = z; }
      for (int c = wv*12; c < wv*12 + 12; ++c) {
        f16x8 bf = *(const f16x8*)(Wlp + (size_t)l15*HDIM + c*32 + q*8);
#pragma unroll
        for (int mt = 0; mt < 8; ++mt) {
          f16x8 a = *(const f16x8*)(h1r + (size_t)(mt*16 + l15)*HDIM + c*32 + q*8);
          a8[mt] = MFMA(a, bf, a8[mt]);
        }
      }
      float* pl = (float*)smem;
#pragma unroll
      for (int mt = 0; mt < 8; ++mt)
#pragma unroll
        for (int rg = 0; rg < 4; ++rg)
          pl[wv*2048 + (mt*16 + q*4 + rg)*16 + l15] = a8[mt][rg];
      __syncthreads();
      for (int e = tid; e < 640; e += 256) {
        int b = e/5, o = e - 5*b;
        out[e] = blin[o] + pl[b*16+o] + pl[2048 + b*16+o] + pl[4096 + b*16+o] + pl[6144 + b*16+o];
      }
    }
  }
}

extern "C" void kernel_launch(void* const* d_in, const int* in_sizes, int n_in,
                              void* d_out, int out_size, void* d_ws, size_t ws_size,
                              hipStream_t stream) {
  (void)in_sizes; (void)n_in; (void)out_size;
  if (ws_size < WS_NEED) return;

  const float* x    = (const float*)d_in[0];
  const float* Wih0 = (const float*)d_in[1];
  const float* Whh0 = (const float*)d_in[2];
  const float* bih0 = (const float*)d_in[3];
  const float* bhh0 = (const float*)d_in[4];
  const float* Wih1 = (const float*)d_in[5];
  const float* Whh1 = (const float*)d_in[6];
  const float* bih1 = (const float*)d_in[7];
  const float* bhh1 = (const float*)d_in[8];
  const float* Wlin = (const float*)d_in[9];
  const float* blin = (const float*)d_in[10];

  char* ws = (char*)d_ws;
  unsigned*  c0l = (unsigned*)(ws + OFF_C0);
  unsigned*  c1l = (unsigned*)(ws + OFF_C1);
  _Float16*  h0b = (_Float16*)(ws + OFF_H0);
  _Float16*  h1b = (_Float16*)(ws + OFF_H1);
  _Float16*  Wp0 = (_Float16*)(ws + OFF_WP0);
  _Float16*  Wp1 = (_Float16*)(ws + OFF_WP1);
  _Float16*  Wlp = (_Float16*)(ws + OFF_WLP);
  float*     out = (float*)d_out;

  hipMemsetAsync(ws, 0, OFF_WP0, stream);   // counters + h rings
  hipLaunchKernelGGL(convert_weights, dim3(4096), dim3(256), 0, stream,
                     Wih0, Whh0, Wih1, Whh1, Wlin, Wp0, Wp1, Wlp);

  hipFuncSetAttribute((const void*)lstm_persistent,
                      hipFuncAttributeMaxDynamicSharedMemorySize, 160*1024);

  void* args[14];
  args[0]  = (void*)&x;    args[1]  = (void*)&bih0; args[2]  = (void*)&bhh0;
  args[3]  = (void*)&bih1; args[4]  = (void*)&bhh1; args[5]  = (void*)&blin;
  args[6]  = (void*)&Wp0;  args[7]  = (void*)&Wp1;  args[8]  = (void*)&Wlp;
  args[9]  = (void*)&h0b;  args[10] = (void*)&h1b;  args[11] = (void*)&c0l;
  args[12] = (void*)&c1l;  args[13] = (void*)&out;
  hipError_t err = hipLaunchCooperativeKernel((const void*)lstm_persistent,
                                              dim3(NBLK), dim3(256),
                                              args, (unsigned)SM_BYTES, stream);
  if (err != hipSuccess) {
    hipLaunchKernelGGL(lstm_persistent, dim3(NBLK), dim3(256), SM_BYTES, stream,
                       x, bih0, bhh0, bih1, bhh1, blin, Wp0, Wp1, Wlp,
                       h0b, h1b, c0l, c1l, out);
  }
}